// Round 4
// baseline (749.925 us; speedup 1.0000x reference)
//
#include <hip/hip_runtime.h>

// Grid constants (match the JAX reference)
#define NX   480
#define NXC  960
#define NS   (480*480)     // 230400 spatial cells (direct / pooled grids)
#define NSC  (960*960)     // 921600 spatial cells ('cen' grids)
#define CC   64            // channels per source
#define BB   2             // batch

typedef float f4v __attribute__((ext_vector_type(4)));

__device__ __forceinline__ void nt_store4(float* p, float a, float b, float c, float d) {
    f4v v = {a, b, c, d};
    __builtin_nontemporal_store(v, (f4v*)p);
}

// Gather 4 consecutive channels of winner w's feature row (0-vector if empty).
__device__ __forceinline__ f4v ld4(int w, const float* __restrict__ f, int c) {
    f4v z = {0.0f, 0.0f, 0.0f, 0.0f};
    if (w < 0) return z;                       // exec-mask predicated
    return *(const f4v*)(f + (size_t)w * CC + c);
}

__device__ __forceinline__ f4v max4(f4v a, f4v b) {
    f4v r;
    r.x = fmaxf(a.x, b.x); r.y = fmaxf(a.y, b.y);
    r.z = fmaxf(a.z, b.z); r.w = fmaxf(a.w, b.w);
    return r;
}

// ---------------------------------------------------------------------------
// Pass 1: winner resolution — last point index wins (atomicMax on p).
// All four sources in one dispatch (blockIdx.y selects the source).
// ---------------------------------------------------------------------------
struct SrcDesc { const int* coords; int* winner; int P; int nx; int ns; };

__global__ void __launch_bounds__(256)
scatter_winner4(SrcDesc s0, SrcDesc s1, SrcDesc s2, SrcDesc s3) {
    SrcDesc d = (blockIdx.y == 0) ? s0 : (blockIdx.y == 1) ? s1
              : (blockIdx.y == 2) ? s2 : s3;
    int p = blockIdx.x * 256 + threadIdx.x;
    if (p >= d.P) return;
    int b = d.coords[4*p + 0];
    int y = d.coords[4*p + 2];
    int x = d.coords[4*p + 3];
    atomicMax(&d.winner[b*d.ns + y*d.nx + x], p);
}

// ---------------------------------------------------------------------------
// Pass 2: dense gather-write. Every output element written exactly once with
// coalesced non-temporal float4 stores. Each thread owns 4 consecutive
// spatial cells × 32 channels. Gathers are vectorized along channels
// (float4 per winner row per 4-channel group) and register-transposed into
// the spatial-float4 stores — 4x fewer gather issues than scalar gathers.
// grid = (NS/1024, B, 2), blockDim = 256.
// ---------------------------------------------------------------------------
__global__ void __launch_bounds__(256)
dense_write(const float* __restrict__ lf,  const float* __restrict__ rf,
            const float* __restrict__ lcf, const float* __restrict__ rcf,
            const int* __restrict__ wl,  const int* __restrict__ wr,
            const int* __restrict__ wlc, const int* __restrict__ wrc,
            float* __restrict__ out_l, float* __restrict__ out_r,
            float* __restrict__ out_cat) {
    int s = (blockIdx.x * 256 + threadIdx.x) * 4;   // first of 4 cells
    int b = blockIdx.y;
    int c0 = blockIdx.z * 32;                        // channel chunk

    // direct winners (4 cells)
    int4 v_l = *(const int4*)(wl + (size_t)b*NS + s);
    int4 v_r = *(const int4*)(wr + (size_t)b*NS + s);
    int wla[4] = {v_l.x, v_l.y, v_l.z, v_l.w};
    int wra[4] = {v_r.x, v_r.y, v_r.z, v_r.w};

    // cen sub-cell winners: rows 2*py, 2*py+1, cols 2*px .. 2*px+7
    int py = s / NX, px = s - py * NX;
    int y0 = py * 2, x0 = px * 2;                    // x0 is 8-aligned
    const int* blc = wlc + (size_t)b * NSC;
    const int* brc = wrc + (size_t)b * NSC;
    int4 lt0 = *(const int4*)(blc + (size_t)y0*NXC + x0);
    int4 lt1 = *(const int4*)(blc + (size_t)y0*NXC + x0 + 4);
    int4 lb0 = *(const int4*)(blc + (size_t)(y0+1)*NXC + x0);
    int4 lb1 = *(const int4*)(blc + (size_t)(y0+1)*NXC + x0 + 4);
    int4 rt0 = *(const int4*)(brc + (size_t)y0*NXC + x0);
    int4 rt1 = *(const int4*)(brc + (size_t)y0*NXC + x0 + 4);
    int4 rb0 = *(const int4*)(brc + (size_t)(y0+1)*NXC + x0);
    int4 rb1 = *(const int4*)(brc + (size_t)(y0+1)*NXC + x0 + 4);
    int lct[8] = {lt0.x, lt0.y, lt0.z, lt0.w, lt1.x, lt1.y, lt1.z, lt1.w};
    int lcb[8] = {lb0.x, lb0.y, lb0.z, lb0.w, lb1.x, lb1.y, lb1.z, lb1.w};
    int rct[8] = {rt0.x, rt0.y, rt0.z, rt0.w, rt1.x, rt1.y, rt1.z, rt1.w};
    int rcb[8] = {rb0.x, rb0.y, rb0.z, rb0.w, rb1.x, rb1.y, rb1.z, rb1.w};

    size_t so  = (size_t)b * CC  * NS + s;   // direct-output base
    size_t co  = (size_t)b * 256 * NS + s;   // cat base

    #pragma unroll 2
    for (int g = 0; g < 8; ++g) {
        int c = c0 + g * 4;                  // 4-channel group (16B-aligned rows)
        f4v vl[4], vr[4], vlc[4], vrc[4];
        #pragma unroll
        for (int j = 0; j < 4; ++j) {
            vl[j] = ld4(wla[j], lf, c);
            vr[j] = ld4(wra[j], rf, c);
            f4v a = ld4(lct[2*j], lcf, c);
            a = max4(a, ld4(lct[2*j+1], lcf, c));
            a = max4(a, ld4(lcb[2*j],   lcf, c));
            a = max4(a, ld4(lcb[2*j+1], lcf, c));
            vlc[j] = a;
            f4v m = ld4(rct[2*j], rcf, c);
            m = max4(m, ld4(rct[2*j+1], rcf, c));
            m = max4(m, ld4(rcb[2*j],   rcf, c));
            m = max4(m, ld4(rcb[2*j+1], rcf, c));
            vrc[j] = m;
        }
        // transpose 4(spatial)x4(channel) tiles into spatial-float4 stores
        #pragma unroll
        for (int k = 0; k < 4; ++k) {
            size_t cs = (size_t)(c + k) * NS;
            nt_store4(out_l   + so + cs,                      vl[0][k],  vl[1][k],  vl[2][k],  vl[3][k]);
            nt_store4(out_r   + so + cs,                      vr[0][k],  vr[1][k],  vr[2][k],  vr[3][k]);
            nt_store4(out_cat + co + cs,                      vl[0][k],  vl[1][k],  vl[2][k],  vl[3][k]);   // ch   0..63
            nt_store4(out_cat + co + (size_t)64*NS  + cs,     vlc[0][k], vlc[1][k], vlc[2][k], vlc[3][k]);  // ch  64..127
            nt_store4(out_cat + co + (size_t)128*NS + cs,     vr[0][k],  vr[1][k],  vr[2][k],  vr[3][k]);   // ch 128..191
            nt_store4(out_cat + co + (size_t)192*NS + cs,     vrc[0][k], vrc[1][k], vrc[2][k], vrc[3][k]);  // ch 192..255
        }
    }
}

extern "C" void kernel_launch(void* const* d_in, const int* in_sizes, int n_in,
                              void* d_out, int out_size, void* d_ws, size_t ws_size,
                              hipStream_t stream) {
    // Inputs per setup_inputs() order
    const float* rc_feat   = (const float*)d_in[0];  // radar_cen
    const int*   rc_coords = (const int*)  d_in[1];
    const float* lc_feat   = (const float*)d_in[2];  // lidar_cen
    const int*   lc_coords = (const int*)  d_in[3];
    const float* l_feat    = (const float*)d_in[4];  // lidar
    const int*   l_coords  = (const int*)  d_in[5];
    const float* r_feat    = (const float*)d_in[6];  // radar
    const int*   r_coords  = (const int*)  d_in[7];

    int P_rc = in_sizes[0] / CC;
    int P_lc = in_sizes[2] / CC;
    int P_l  = in_sizes[4] / CC;
    int P_r  = in_sizes[6] / CC;

    // Output layout (flat, in return order): lidar, radar, cat
    float* out_lidar = (float*)d_out;                 // [2,64,480,480]
    float* out_radar = out_lidar + (size_t)BB*CC*NS;  // [2,64,480,480]
    float* out_cat   = out_radar + (size_t)BB*CC*NS;  // [2,256,480,480]

    // Workspace: winner grids only, init -1 (memset 0xFF)
    int* w_l  = (int*)d_ws;          // [B*NS]
    int* w_r  = w_l  + BB*NS;        // [B*NS]
    int* w_lc = w_r  + BB*NS;        // [B*NSC]
    int* w_rc = w_lc + BB*NSC;       // [B*NSC]
    size_t ws_bytes = (size_t)(2*BB*NS + 2*BB*NSC) * sizeof(int);  // ~18.4 MB

    hipMemsetAsync(d_ws, 0xFF, ws_bytes, stream);

    // Pass 1: winner resolution, one dispatch for all four sources
    SrcDesc s_l  = { l_coords,  w_l,  P_l,  NX,  NS  };
    SrcDesc s_r  = { r_coords,  w_r,  P_r,  NX,  NS  };
    SrcDesc s_lc = { lc_coords, w_lc, P_lc, NXC, NSC };
    SrcDesc s_rc = { rc_coords, w_rc, P_rc, NXC, NSC };
    int maxP = max(max(P_l, P_r), max(P_lc, P_rc));
    dim3 wgrid((maxP + 255) / 256, 4);
    scatter_winner4<<<wgrid, 256, 0, stream>>>(s_l, s_r, s_lc, s_rc);

    // Pass 2: dense gather-write of all 708 MB, fully coalesced nt-stores
    dim3 grid(NS / (256 * 4), BB, 2);
    dense_write<<<grid, 256, 0, stream>>>(l_feat, r_feat, lc_feat, rc_feat,
                                          w_l, w_r, w_lc, w_rc,
                                          out_lidar, out_radar, out_cat);
}

// Round 5
// 730.320 us; speedup vs baseline: 1.0268x; 1.0268x over previous
//
#include <hip/hip_runtime.h>

// Grid constants (match the JAX reference)
#define NX   480
#define NXC  960
#define NS   (480*480)     // 230400 spatial cells (direct / pooled grids)
#define NSC  (960*960)     // 921600 spatial cells ('cen' grids)
#define CC   64            // channels per source
#define BB   2             // batch

typedef float f4v __attribute__((ext_vector_type(4)));

__device__ __forceinline__ void nt_store4(float* p, float a, float b, float c, float d) {
    f4v v = {a, b, c, d};
    __builtin_nontemporal_store(v, (f4v*)p);
}

// Gather 4 consecutive channels of winner w's feature row (0-vector if empty).
__device__ __forceinline__ f4v ld4(int w, const float* __restrict__ f, int c) {
    f4v z = {0.0f, 0.0f, 0.0f, 0.0f};
    if (w < 0) return z;                       // exec-mask predicated
    return *(const f4v*)(f + (size_t)w * CC + c);
}

__device__ __forceinline__ f4v max4(f4v a, f4v b) {
    f4v r;
    r.x = fmaxf(a.x, b.x); r.y = fmaxf(a.y, b.y);
    r.z = fmaxf(a.z, b.z); r.w = fmaxf(a.w, b.w);
    return r;
}

// ---------------------------------------------------------------------------
// Pass 1: winner resolution — last point index wins (atomicMax on p).
// All four sources in one dispatch (blockIdx.y selects the source).
// ---------------------------------------------------------------------------
struct SrcDesc { const int* coords; int* winner; int P; int nx; int ns; };

__global__ void __launch_bounds__(256)
scatter_winner4(SrcDesc s0, SrcDesc s1, SrcDesc s2, SrcDesc s3) {
    SrcDesc d = (blockIdx.y == 0) ? s0 : (blockIdx.y == 1) ? s1
              : (blockIdx.y == 2) ? s2 : s3;
    int p = blockIdx.x * 256 + threadIdx.x;
    if (p >= d.P) return;
    int b = d.coords[4*p + 0];
    int y = d.coords[4*p + 2];
    int x = d.coords[4*p + 3];
    atomicMax(&d.winner[b*d.ns + y*d.nx + x], p);
}

// ---------------------------------------------------------------------------
// Pass 2: dense gather-write. Every output element written exactly once with
// coalesced non-temporal float4 stores. Each thread owns 4 consecutive
// spatial cells × 16 channels (z picks the 16-channel chunk; z=4 gives 1800
// blocks ≈ 7 blocks/CU so gather-miss latency is covered by other waves'
// store streams). Gathers are channel-vectorized (one float4 per winner row
// per 4-channel group); unroll 1 keeps one gather group live (~130 VGPR,
// 3 waves/SIMD) — R4's unroll-2 at ~200 VGPR halved occupancy and regressed.
// ---------------------------------------------------------------------------
__global__ void __launch_bounds__(256)
dense_write(const float* __restrict__ lf,  const float* __restrict__ rf,
            const float* __restrict__ lcf, const float* __restrict__ rcf,
            const int* __restrict__ wl,  const int* __restrict__ wr,
            const int* __restrict__ wlc, const int* __restrict__ wrc,
            float* __restrict__ out_l, float* __restrict__ out_r,
            float* __restrict__ out_cat) {
    int s = (blockIdx.x * 256 + threadIdx.x) * 4;   // first of 4 cells
    int b = blockIdx.y;
    int c0 = blockIdx.z * 16;                        // channel chunk

    // direct winners (4 cells)
    int4 v_l = *(const int4*)(wl + (size_t)b*NS + s);
    int4 v_r = *(const int4*)(wr + (size_t)b*NS + s);
    int wla[4] = {v_l.x, v_l.y, v_l.z, v_l.w};
    int wra[4] = {v_r.x, v_r.y, v_r.z, v_r.w};

    // cen sub-cell winners: rows 2*py, 2*py+1, cols 2*px .. 2*px+7
    int py = s / NX, px = s - py * NX;
    int y0 = py * 2, x0 = px * 2;                    // x0 is 8-aligned
    const int* blc = wlc + (size_t)b * NSC;
    const int* brc = wrc + (size_t)b * NSC;
    int4 lt0 = *(const int4*)(blc + (size_t)y0*NXC + x0);
    int4 lt1 = *(const int4*)(blc + (size_t)y0*NXC + x0 + 4);
    int4 lb0 = *(const int4*)(blc + (size_t)(y0+1)*NXC + x0);
    int4 lb1 = *(const int4*)(blc + (size_t)(y0+1)*NXC + x0 + 4);
    int4 rt0 = *(const int4*)(brc + (size_t)y0*NXC + x0);
    int4 rt1 = *(const int4*)(brc + (size_t)y0*NXC + x0 + 4);
    int4 rb0 = *(const int4*)(brc + (size_t)(y0+1)*NXC + x0);
    int4 rb1 = *(const int4*)(brc + (size_t)(y0+1)*NXC + x0 + 4);
    int lct[8] = {lt0.x, lt0.y, lt0.z, lt0.w, lt1.x, lt1.y, lt1.z, lt1.w};
    int lcb[8] = {lb0.x, lb0.y, lb0.z, lb0.w, lb1.x, lb1.y, lb1.z, lb1.w};
    int rct[8] = {rt0.x, rt0.y, rt0.z, rt0.w, rt1.x, rt1.y, rt1.z, rt1.w};
    int rcb[8] = {rb0.x, rb0.y, rb0.z, rb0.w, rb1.x, rb1.y, rb1.z, rb1.w};

    size_t so  = (size_t)b * CC  * NS + s;   // direct-output base
    size_t co  = (size_t)b * 256 * NS + s;   // cat base

    #pragma unroll 1
    for (int g = 0; g < 4; ++g) {
        int c = c0 + g * 4;                  // 4-channel group (16B-aligned rows)
        f4v vl[4], vr[4], vlc[4], vrc[4];
        #pragma unroll
        for (int j = 0; j < 4; ++j) {
            vl[j] = ld4(wla[j], lf, c);
            vr[j] = ld4(wra[j], rf, c);
            f4v a = ld4(lct[2*j], lcf, c);
            a = max4(a, ld4(lct[2*j+1], lcf, c));
            a = max4(a, ld4(lcb[2*j],   lcf, c));
            a = max4(a, ld4(lcb[2*j+1], lcf, c));
            vlc[j] = a;
            f4v m = ld4(rct[2*j], rcf, c);
            m = max4(m, ld4(rct[2*j+1], rcf, c));
            m = max4(m, ld4(rcb[2*j],   rcf, c));
            m = max4(m, ld4(rcb[2*j+1], rcf, c));
            vrc[j] = m;
        }
        // transpose 4(spatial)x4(channel) tiles into spatial-float4 stores
        #pragma unroll
        for (int k = 0; k < 4; ++k) {
            size_t cs = (size_t)(c + k) * NS;
            nt_store4(out_l   + so + cs,                      vl[0][k],  vl[1][k],  vl[2][k],  vl[3][k]);
            nt_store4(out_r   + so + cs,                      vr[0][k],  vr[1][k],  vr[2][k],  vr[3][k]);
            nt_store4(out_cat + co + cs,                      vl[0][k],  vl[1][k],  vl[2][k],  vl[3][k]);   // ch   0..63
            nt_store4(out_cat + co + (size_t)64*NS  + cs,     vlc[0][k], vlc[1][k], vlc[2][k], vlc[3][k]);  // ch  64..127
            nt_store4(out_cat + co + (size_t)128*NS + cs,     vr[0][k],  vr[1][k],  vr[2][k],  vr[3][k]);   // ch 128..191
            nt_store4(out_cat + co + (size_t)192*NS + cs,     vrc[0][k], vrc[1][k], vrc[2][k], vrc[3][k]);  // ch 192..255
        }
    }
}

extern "C" void kernel_launch(void* const* d_in, const int* in_sizes, int n_in,
                              void* d_out, int out_size, void* d_ws, size_t ws_size,
                              hipStream_t stream) {
    // Inputs per setup_inputs() order
    const float* rc_feat   = (const float*)d_in[0];  // radar_cen
    const int*   rc_coords = (const int*)  d_in[1];
    const float* lc_feat   = (const float*)d_in[2];  // lidar_cen
    const int*   lc_coords = (const int*)  d_in[3];
    const float* l_feat    = (const float*)d_in[4];  // lidar
    const int*   l_coords  = (const int*)  d_in[5];
    const float* r_feat    = (const float*)d_in[6];  // radar
    const int*   r_coords  = (const int*)  d_in[7];

    int P_rc = in_sizes[0] / CC;
    int P_lc = in_sizes[2] / CC;
    int P_l  = in_sizes[4] / CC;
    int P_r  = in_sizes[6] / CC;

    // Output layout (flat, in return order): lidar, radar, cat
    float* out_lidar = (float*)d_out;                 // [2,64,480,480]
    float* out_radar = out_lidar + (size_t)BB*CC*NS;  // [2,64,480,480]
    float* out_cat   = out_radar + (size_t)BB*CC*NS;  // [2,256,480,480]

    // Workspace: winner grids only, init -1 (memset 0xFF)
    int* w_l  = (int*)d_ws;          // [B*NS]
    int* w_r  = w_l  + BB*NS;        // [B*NS]
    int* w_lc = w_r  + BB*NS;        // [B*NSC]
    int* w_rc = w_lc + BB*NSC;       // [B*NSC]
    size_t ws_bytes = (size_t)(2*BB*NS + 2*BB*NSC) * sizeof(int);  // ~18.4 MB

    hipMemsetAsync(d_ws, 0xFF, ws_bytes, stream);

    // Pass 1: winner resolution, one dispatch for all four sources
    SrcDesc s_l  = { l_coords,  w_l,  P_l,  NX,  NS  };
    SrcDesc s_r  = { r_coords,  w_r,  P_r,  NX,  NS  };
    SrcDesc s_lc = { lc_coords, w_lc, P_lc, NXC, NSC };
    SrcDesc s_rc = { rc_coords, w_rc, P_rc, NXC, NSC };
    int maxP = max(max(P_l, P_r), max(P_lc, P_rc));
    dim3 wgrid((maxP + 255) / 256, 4);
    scatter_winner4<<<wgrid, 256, 0, stream>>>(s_l, s_r, s_lc, s_rc);

    // Pass 2: dense gather-write of all 708 MB, fully coalesced nt-stores
    dim3 grid(NS / (256 * 4), BB, 4);
    dense_write<<<grid, 256, 0, stream>>>(l_feat, r_feat, lc_feat, rc_feat,
                                          w_l, w_r, w_lc, w_rc,
                                          out_lidar, out_radar, out_cat);
}